// Round 1
// baseline (1445.720 us; speedup 1.0000x reference)
//
#include <hip/hip_runtime.h>
#include <cmath>

typedef float    f32x4 __attribute__((ext_vector_type(4)));
typedef _Float16 f16x8 __attribute__((ext_vector_type(8)));

#define T_NUM 4096
#define H_DIM 1024
#define I_DIM 4096

// ---- meta layout (int32 indices into the meta block) ----
#define M_COUNTS   0      // [3][2][8]
#define M_CURSORS  48     // [3][2][8]
#define M_OFFSETS  96     // [3][2][8]  (global slot offset within layer, [0,8192))
#define M_NTILES   144    // [3][2]
#define M_TILE_E   152    // [6][40]
#define M_TILE_M   392    // [6][40]
#define M_TOPKI    1024   // int  [3][4096][2]
#define M_TOPKP    25600  // f32  [3][4096][2]
#define M_STOK     50176  // int  [3][8192]
#define M_SPRB     74752  // f32  [3][8192]
#define MAXTILES   40

__device__ __forceinline__ float wave_sum(float v) {
  v += __shfl_xor(v, 32);
  v += __shfl_xor(v, 16);
  v += __shfl_xor(v, 8);
  v += __shfl_xor(v, 4);
  v += __shfl_xor(v, 2);
  v += __shfl_xor(v, 1);
  return v;
}

// top-2 + softmax, fp32, tie semantics = lax.top_k (lower index first)
__device__ __forceinline__ void topk_write(int* meta, int layer, int t, const float* v) {
  int e0 = 0; float v0 = v[0];
  #pragma unroll
  for (int e = 1; e < 8; ++e) { if (v[e] > v0) { v0 = v[e]; e0 = e; } }
  int e1 = 0; float v1 = -3.4e38f;
  #pragma unroll
  for (int e = 0; e < 8; ++e) { if (e != e0 && v[e] > v1) { v1 = v[e]; e1 = e; } }
  float ex = expf(v1 - v0);
  float p0 = 1.f / (1.f + ex);
  float p1 = ex / (1.f + ex);
  meta[M_TOPKI + (layer * T_NUM + t) * 2    ] = e0;
  meta[M_TOPKI + (layer * T_NUM + t) * 2 + 1] = e1;
  ((float*)meta)[M_TOPKP + (layer * T_NUM + t) * 2    ] = p0;
  ((float*)meta)[M_TOPKP + (layer * T_NUM + t) * 2 + 1] = p1;
  atomicAdd(&meta[M_COUNTS + (layer * 2 + 0) * 8 + e0], 1);
  atomicAdd(&meta[M_COUNTS + (layer * 2 + 1) * 8 + e1], 1);
}

// gate+up router logits from x, fp32 exact-ish. 1 wave per token, 4 tokens/block.
__global__ __launch_bounds__(256) void router_gu(const float* __restrict__ x,
    const float* __restrict__ Rg, const float* __restrict__ Ru, int* __restrict__ meta)
{
  int w = threadIdx.x >> 6, lane = threadIdx.x & 63;
  int t = blockIdx.x * 4 + w;
  const float* xr = x + (size_t)t * H_DIM + lane * 4;
  f32x4 xv[4];
  #pragma unroll
  for (int c = 0; c < 4; ++c) xv[c] = *(const f32x4*)(xr + c * 256);
  float lg[8], lu[8];
  #pragma unroll
  for (int e = 0; e < 8; ++e) {
    const float* rg = Rg + (size_t)e * H_DIM + lane * 4;
    const float* ru = Ru + (size_t)e * H_DIM + lane * 4;
    float sg = 0.f, su = 0.f;
    #pragma unroll
    for (int c = 0; c < 4; ++c) {
      f32x4 a = *(const f32x4*)(rg + c * 256);
      f32x4 b = *(const f32x4*)(ru + c * 256);
      sg += a[0]*xv[c][0] + a[1]*xv[c][1] + a[2]*xv[c][2] + a[3]*xv[c][3];
      su += b[0]*xv[c][0] + b[1]*xv[c][1] + b[2]*xv[c][2] + b[3]*xv[c][3];
    }
    lg[e] = wave_sum(sg);
    lu[e] = wave_sum(su);
  }
  if (lane == 0) {
    topk_write(meta, 0, t, lg);
    topk_write(meta, 1, t, lu);
  }
}

__global__ __launch_bounds__(256) void router_down(const float* __restrict__ inter,
    const float* __restrict__ Rd, int* __restrict__ meta)
{
  int w = threadIdx.x >> 6, lane = threadIdx.x & 63;
  int t = blockIdx.x * 4 + w;
  const float* xr = inter + (size_t)t * I_DIM + lane * 4;
  f32x4 xv[16];
  #pragma unroll
  for (int c = 0; c < 16; ++c) xv[c] = *(const f32x4*)(xr + c * 256);
  float ld[8];
  #pragma unroll
  for (int e = 0; e < 8; ++e) {
    const float* rr = Rd + (size_t)e * I_DIM + lane * 4;
    float s = 0.f;
    #pragma unroll
    for (int c = 0; c < 16; ++c) {
      f32x4 a = *(const f32x4*)(rr + c * 256);
      s += a[0]*xv[c][0] + a[1]*xv[c][1] + a[2]*xv[c][2] + a[3]*xv[c][3];
    }
    ld[e] = wave_sum(s);
  }
  if (lane == 0) topk_write(meta, 2, t, ld);
}

// single-thread: segment offsets + M-tile table (<=39 tiles per (layer,k))
__global__ void scan_tiles(int* meta, int l0, int nl) {
  if (threadIdx.x != 0 || blockIdx.x != 0) return;
  for (int l = l0; l < l0 + nl; ++l) {
    int off = 0;
    for (int k = 0; k < 2; ++k) {
      int nt = 0;
      for (int e = 0; e < 8; ++e) {
        int s = (l * 2 + k) * 8 + e;
        meta[M_OFFSETS + s] = off;
        int c = meta[M_COUNTS + s];
        for (int m = 0; m < c; m += 128) {
          meta[M_TILE_E + (l * 2 + k) * MAXTILES + nt] = e;
          meta[M_TILE_M + (l * 2 + k) * MAXTILES + nt] = m;
          ++nt;
        }
        off += c;
      }
      meta[M_NTILES + l * 2 + k] = nt;
    }
  }
}

__global__ __launch_bounds__(256) void assign_slots(int* meta, int l0, int nl) {
  int t = blockIdx.x * blockDim.x + threadIdx.x;
  if (t >= T_NUM) return;
  for (int l = l0; l < l0 + nl; ++l) {
    #pragma unroll
    for (int k = 0; k < 2; ++k) {
      int e  = meta[M_TOPKI + (l * T_NUM + t) * 2 + k];
      float p = ((float*)meta)[M_TOPKP + (l * T_NUM + t) * 2 + k];
      int s = (l * 2 + k) * 8 + e;
      int pos = meta[M_OFFSETS + s] + atomicAdd(&meta[M_CURSORS + s], 1);
      meta[M_STOK + l * 8192 + pos] = t;
      ((float*)meta)[M_SPRB + l * 8192 + pos] = p;
    }
  }
}

template<int SPLITS>
__device__ __forceinline__ void cvt_store(_Float16* __restrict__ hi, _Float16* __restrict__ lo,
                                          int idx, f32x4 a, f32x4 b)
{
  f16x8 h, l;
  #pragma unroll
  for (int j = 0; j < 4; ++j) {
    _Float16 ha = (_Float16)a[j];
    _Float16 hb = (_Float16)b[j];
    h[j] = ha; h[j + 4] = hb;
    if constexpr (SPLITS == 3) {
      l[j]     = (_Float16)(a[j] - (float)ha);
      l[j + 4] = (_Float16)(b[j] - (float)hb);
    }
  }
  *(f16x8*)(hi + idx) = h;
  if constexpr (SPLITS == 3) *(f16x8*)(lo + idx) = l;
}

__device__ __forceinline__ f32x4 mfma16(f16x8 a, f16x8 b, f32x4 c) {
  return __builtin_amdgcn_mfma_f32_16x16x32_f16(a, b, c, 0, 0, 0);
}

// Routed GEMM: out[tok, n] (+)= p * sum_k A[tok,k] * W[e,n,k]
// 128x128 tile, BK=32, 4 waves (64x64 each), split-f16 (SPLITS=3) or plain f16 (SPLITS=1).
// ADD=0: store (k=0 pass), ADD=1: rmw add (k=1 pass) -> race-free, no atomics.
template<int SPLITS, int ADD>
__global__ __launch_bounds__(256) void moe_gemm(
    const float* __restrict__ Asrc, const float* __restrict__ Wsrc,
    float* __restrict__ Out, const int* __restrict__ meta,
    int layer, int kk, int K, int N)
{
  int pass = layer * 2 + kk;
  if ((int)blockIdx.x >= meta[M_NTILES + pass]) return;
  int e   = meta[M_TILE_E + pass * MAXTILES + blockIdx.x];
  int m0  = meta[M_TILE_M + pass * MAXTILES + blockIdx.x];
  int s   = pass * 8 + e;
  int cnt = meta[M_COUNTS + s];
  int seg = meta[M_OFFSETS + s];
  int n0  = blockIdx.y * 128;

  constexpr int LDK = 40;  // 32 + 8 pad (halves): conflict-light, keeps 16B alignment
  __shared__ __align__(16) _Float16 sA[128 * LDK];
  __shared__ __align__(16) _Float16 sB[128 * LDK];
  __shared__ __align__(16) _Float16 sAl[SPLITS == 3 ? 128 * LDK : 8];
  __shared__ __align__(16) _Float16 sBl[SPLITS == 3 ? 128 * LDK : 8];
  __shared__ int   s_tok[128];
  __shared__ float s_prb[128];

  int tid = threadIdx.x;
  if (tid < 128) {
    int m = m0 + tid; if (m >= cnt) m = cnt - 1;   // clamp (cnt>=1 when tile exists)
    s_tok[tid] = meta[M_STOK + layer * 8192 + seg + m];
    s_prb[tid] = ((const float*)meta)[M_SPRB + layer * 8192 + seg + m];
  }
  __syncthreads();

  int r = tid >> 1, hh = tid & 1;  // staging: 2 threads per row, 16 floats each
  const float* pa = Asrc + (size_t)s_tok[r] * K + hh * 16;
  const float* pb = Wsrc + ((size_t)e * N + (n0 + r)) * K + hh * 16;

  int lane = tid & 63, w = tid >> 6;
  int wr = w >> 1, wc = w & 1;
  int fr = lane & 15, fq = lane >> 4;
  int aoff = (wr * 64 + fr) * LDK + fq * 8;
  int boff = (wc * 64 + fr) * LDK + fq * 8;

  f32x4 acc[4][4];
  #pragma unroll
  for (int i = 0; i < 4; ++i)
    #pragma unroll
    for (int j = 0; j < 4; ++j) acc[i][j] = f32x4{0.f, 0.f, 0.f, 0.f};

  const int KT = K >> 5;
  for (int kt = 0; kt < KT; ++kt) {
    f32x4 va0 = *(const f32x4*)(pa);
    f32x4 va1 = *(const f32x4*)(pa + 4);
    f32x4 va2 = *(const f32x4*)(pa + 8);
    f32x4 va3 = *(const f32x4*)(pa + 12);
    f32x4 vb0 = *(const f32x4*)(pb);
    f32x4 vb1 = *(const f32x4*)(pb + 4);
    f32x4 vb2 = *(const f32x4*)(pb + 8);
    f32x4 vb3 = *(const f32x4*)(pb + 12);
    pa += 32; pb += 32;
    __syncthreads();                       // previous tile's LDS reads done
    int wb = r * LDK + hh * 16;
    cvt_store<SPLITS>(sA, sAl, wb,     va0, va1);
    cvt_store<SPLITS>(sA, sAl, wb + 8, va2, va3);
    cvt_store<SPLITS>(sB, sBl, wb,     vb0, vb1);
    cvt_store<SPLITS>(sB, sBl, wb + 8, vb2, vb3);
    __syncthreads();

    f16x8 ah[4], bh[4];
    #pragma unroll
    for (int mi = 0; mi < 4; ++mi) ah[mi] = *(const f16x8*)(sA + aoff + mi * 16 * LDK);
    #pragma unroll
    for (int ni = 0; ni < 4; ++ni) bh[ni] = *(const f16x8*)(sB + boff + ni * 16 * LDK);
    #pragma unroll
    for (int mi = 0; mi < 4; ++mi)
      #pragma unroll
      for (int ni = 0; ni < 4; ++ni)
        acc[mi][ni] = mfma16(ah[mi], bh[ni], acc[mi][ni]);
    if constexpr (SPLITS == 3) {
      f16x8 tl[4];
      #pragma unroll
      for (int ni = 0; ni < 4; ++ni) tl[ni] = *(const f16x8*)(sBl + boff + ni * 16 * LDK);
      #pragma unroll
      for (int mi = 0; mi < 4; ++mi)
        #pragma unroll
        for (int ni = 0; ni < 4; ++ni)
          acc[mi][ni] = mfma16(ah[mi], tl[ni], acc[mi][ni]);
      #pragma unroll
      for (int mi = 0; mi < 4; ++mi) tl[mi] = *(const f16x8*)(sAl + aoff + mi * 16 * LDK);
      #pragma unroll
      for (int mi = 0; mi < 4; ++mi)
        #pragma unroll
        for (int ni = 0; ni < 4; ++ni)
          acc[mi][ni] = mfma16(tl[mi], bh[ni], acc[mi][ni]);
    }
  }

  // epilogue: C layout col=lane&15, row=(lane>>4)*4+j  (m89-verified mapping)
  #pragma unroll
  for (int mi = 0; mi < 4; ++mi) {
    #pragma unroll
    for (int jj = 0; jj < 4; ++jj) {
      int lm = wr * 64 + mi * 16 + fq * 4 + jj;
      int gm = m0 + lm;
      if (gm < cnt) {
        int tok = s_tok[lm];
        float p = s_prb[lm];
        float* orow = Out + (size_t)tok * N + n0 + wc * 64 + fr;
        #pragma unroll
        for (int ni = 0; ni < 4; ++ni) {
          float v = p * acc[mi][ni][jj];
          if constexpr (ADD) orow[ni * 16] += v; else orow[ni * 16] = v;
        }
      }
    }
  }
}

__global__ __launch_bounds__(256) void swiglu_kernel(float* __restrict__ g,
                                                     const float* __restrict__ u)
{
  size_t i = ((size_t)blockIdx.x * blockDim.x + threadIdx.x) * 4;
  f32x4 gv = *(const f32x4*)(g + i);
  f32x4 uv = *(const f32x4*)(u + i);
  #pragma unroll
  for (int j = 0; j < 4; ++j) {
    float xx = gv[j];
    gv[j] = (xx / (1.f + expf(-xx))) * uv[j];
  }
  *(f32x4*)(g + i) = gv;
}

extern "C" void kernel_launch(void* const* d_in, const int* in_sizes, int n_in,
                              void* d_out, int out_size, void* d_ws, size_t ws_size,
                              hipStream_t stream)
{
  const float* x  = (const float*)d_in[0];
  const float* Rg = (const float*)d_in[1];
  const float* Wg = (const float*)d_in[2];
  const float* Ru = (const float*)d_in[3];
  const float* Wu = (const float*)d_in[4];
  const float* Rd = (const float*)d_in[5];
  const float* Wd = (const float*)d_in[6];
  float* out = (float*)d_out;
  char* ws = (char*)d_ws;
  float* g   = (float*)ws;                              // [T, I] fp32, 67MB
  float* u   = (float*)(ws + (size_t)67108864);         // [T, I] fp32, 67MB
  int*  meta = (int*)(ws + (size_t)134217728);          // ~0.4MB

  hipMemsetAsync(meta, 0, 4096, stream);  // counts/cursors/ntiles
  router_gu<<<dim3(T_NUM / 4), 256, 0, stream>>>(x, Rg, Ru, meta);
  scan_tiles<<<dim3(1), 1, 0, stream>>>(meta, 0, 2);
  assign_slots<<<dim3(T_NUM / 256), 256, 0, stream>>>(meta, 0, 2);

  moe_gemm<3, 0><<<dim3(MAXTILES, 32), 256, 0, stream>>>(x, Wg, g, meta, 0, 0, H_DIM, I_DIM);
  moe_gemm<3, 1><<<dim3(MAXTILES, 32), 256, 0, stream>>>(x, Wg, g, meta, 0, 1, H_DIM, I_DIM);
  moe_gemm<3, 0><<<dim3(MAXTILES, 32), 256, 0, stream>>>(x, Wu, u, meta, 1, 0, H_DIM, I_DIM);
  moe_gemm<3, 1><<<dim3(MAXTILES, 32), 256, 0, stream>>>(x, Wu, u, meta, 1, 1, H_DIM, I_DIM);

  swiglu_kernel<<<dim3(T_NUM * (I_DIM / 1024)), 256, 0, stream>>>(g, u);

  router_down<<<dim3(T_NUM / 4), 256, 0, stream>>>(g, Rd, meta);
  scan_tiles<<<dim3(1), 1, 0, stream>>>(meta, 2, 1);
  assign_slots<<<dim3(T_NUM / 256), 256, 0, stream>>>(meta, 2, 1);

  moe_gemm<1, 0><<<dim3(MAXTILES, 8), 256, 0, stream>>>(g, Wd, out, meta, 2, 0, I_DIM, H_DIM);
  moe_gemm<1, 1><<<dim3(MAXTILES, 8), 256, 0, stream>>>(g, Wd, out, meta, 2, 1, I_DIM, H_DIM);
}